// Round 7
// baseline (348.343 us; speedup 1.0000x reference)
//
#include <hip/hip_runtime.h>
#include <stdint.h>

// Problem constants (B,T,D,H fixed by the reference)
#define B_SZ 2
#define T_SEQ 2048
#define DMODEL 1024
#define NHEAD 16
#define DKH 64
#define M_ROWS (B_SZ * T_SEQ)   // 4096

#define LDT 72    // attn sK row stride: 144B rows, 2-way bank aliasing = free (m136)
#define LDP 136   // attn sV/sP row stride for 128-wide tiles: 272B rows, 2-way = free

#define INP_E  4194304u   // 4M elems per input tensor
#define W_E    1048576u   // 1M elems per weight

typedef __bf16 bf16x8 __attribute__((ext_vector_type(8)));
typedef float  f32x4  __attribute__((ext_vector_type(4)));

__device__ __forceinline__ unsigned short f2bf(float f) {
    unsigned u = __builtin_bit_cast(unsigned, f);
    u += 0x7fffu + ((u >> 16) & 1u);   // RNE
    return (unsigned short)(u >> 16);
}
// 8 consecutive fp32 -> 8 bf16 packed in a uint4
__device__ __forceinline__ uint4 cvt8(const float* p) {
    float4 f0 = *(const float4*)p, f1 = *(const float4*)(p + 4);
    uint4 r;
    r.x = (unsigned)f2bf(f0.x) | ((unsigned)f2bf(f0.y) << 16);
    r.y = (unsigned)f2bf(f0.z) | ((unsigned)f2bf(f0.w) << 16);
    r.z = (unsigned)f2bf(f1.x) | ((unsigned)f2bf(f1.y) << 16);
    r.w = (unsigned)f2bf(f1.z) | ((unsigned)f2bf(f1.w) << 16);
    return r;
}

// Async global->LDS, 16B per lane. LDS dest = wave-uniform base + lane*16 (m104/m108).
__device__ __forceinline__ void async16(const unsigned short* g, unsigned short* l) {
    __builtin_amdgcn_global_load_lds(
        (const __attribute__((address_space(1))) void*)g,
        (__attribute__((address_space(3))) void*)l, 16, 0, 0);
}

// One-shot fp32 -> bf16 conversion of q,k,v + 4 weights into ws.
__global__ __launch_bounds__(256) void cvt_all(
    const float* __restrict__ q, const float* __restrict__ k, const float* __restrict__ v,
    const float* __restrict__ wq, const float* __restrict__ wk,
    const float* __restrict__ wv, const float* __restrict__ wo,
    unsigned short* __restrict__ wsb)
{
    int blk = blockIdx.x;
    const float* src; unsigned short* dst; int lb;
    if      (blk < 2048) { src = q;  dst = wsb;                       lb = blk; }
    else if (blk < 4096) { src = k;  dst = wsb + INP_E;               lb = blk - 2048; }
    else if (blk < 6144) { src = v;  dst = wsb + 2 * INP_E;           lb = blk - 4096; }
    else if (blk < 6656) { src = wq; dst = wsb + 3 * INP_E;           lb = blk - 6144; }
    else if (blk < 7168) { src = wk; dst = wsb + 3 * INP_E + W_E;     lb = blk - 6656; }
    else if (blk < 7680) { src = wv; dst = wsb + 3 * INP_E + 2 * W_E; lb = blk - 7168; }
    else                 { src = wo; dst = wsb + 3 * INP_E + 3 * W_E; lb = blk - 7680; }
    size_t i = ((size_t)lb * 256 + threadIdx.x) * 8;
    *(uint4*)&dst[i] = cvt8(src + i);
}

// ---------------- m97-style GEMM core ----------------
// D[m][n] = sum_k A[m][k]*W[n][k] + bias. Tile (MT*32) x 128, BK=64,
// global_load_lds width=16 into UNPADDED stride-64 LDS with XOR column-chunk
// swizzle (LDS[row][j] holds global chunk j^(row&7); reads un-swizzle).
// C_MODE: 0 = bf16 C[m*N+n] (bias[n]); 1 = fp32 C (bias[n]);
//         2 = Vt[(b*1024+m)*2048 + t] (bias[m], transposed store).
// MT: M-subtiles per wave (4 -> 128x128 tile; 2 -> 64x128 tile for 2 blocks/CU).
template<int C_MODE, int MT>
__device__ __forceinline__ void gemm_core(
    const unsigned short* __restrict__ A, const unsigned short* __restrict__ W,
    const float* __restrict__ bias, void* __restrict__ C,
    int N, int K, int bx, int by,
    unsigned short* sA, unsigned short* sB)
{
    const int tid  = threadIdx.x;
    const int wave = tid >> 6, lane = tid & 63;
    const int quad = lane >> 4, l15 = lane & 15;
    const int TM = MT * 32;
    const int m0 = by * TM, n0 = bx * 128;
    const int wm = (wave & 1) * (MT * 16), wn = (wave >> 1) * 64;

    f32x4 acc[MT][4] = {};

    for (int k0 = 0; k0 < K; k0 += 64) {
        __syncthreads();                      // prev iteration's LDS reads done
        #pragma unroll
        for (int i = 0; i < MT; i++) {        // A: TM rows x 8 chunks
            int c   = tid + 256 * i;
            int row = c >> 3;
            int gk  = ((c & 7) ^ (row & 7)) * 8;
            int sb  = (wave * 64 + 256 * i) * 8;
            async16(&A[(size_t)(m0 + row) * K + k0 + gk], sA + sb);
        }
        #pragma unroll
        for (int i = 0; i < 4; i++) {         // B: 128 rows x 8 chunks
            int c   = tid + 256 * i;
            int row = c >> 3;
            int gk  = ((c & 7) ^ (row & 7)) * 8;
            int sb  = (wave * 64 + 256 * i) * 8;
            async16(&W[(size_t)(n0 + row) * K + k0 + gk], sB + sb);
        }
        __syncthreads();                      // drains vmcnt(0): data landed
        const int sw = l15 & 7;
        #pragma unroll
        for (int ks = 0; ks < 2; ks++) {
            bf16x8 af[MT], bfv[4];
            #pragma unroll
            for (int mt = 0; mt < MT; mt++)
                af[mt] = *(const bf16x8*)&sA[(wm + mt * 16 + l15) * 64 +
                                             (((ks * 4 + quad) ^ sw) * 8)];
            #pragma unroll
            for (int nt = 0; nt < 4; nt++)
                bfv[nt] = *(const bf16x8*)&sB[(wn + nt * 16 + l15) * 64 +
                                              (((ks * 4 + quad) ^ sw) * 8)];
            #pragma unroll
            for (int mt = 0; mt < MT; mt++)
                #pragma unroll
                for (int nt = 0; nt < 4; nt++)
                    acc[mt][nt] = __builtin_amdgcn_mfma_f32_16x16x32_bf16(
                        af[mt], bfv[nt], acc[mt][nt], 0, 0, 0);
        }
    }

    if (C_MODE == 2) {
        #pragma unroll
        for (int mt = 0; mt < MT; mt++) {
            #pragma unroll
            for (int r = 0; r < 4; r++) {
                int m = m0 + wm + mt * 16 + quad * 4 + r;
                float bm = bias[m];
                #pragma unroll
                for (int nt = 0; nt < 4; nt++) {
                    int n = n0 + wn + nt * 16 + l15;
                    int bb = n >> 11, t = n & 2047;
                    ((unsigned short*)C)[((size_t)bb * 1024 + m) * 2048 + t] =
                        f2bf(acc[mt][nt][r] + bm);
                }
            }
        }
    } else {
        #pragma unroll
        for (int nt = 0; nt < 4; nt++) {
            int n = n0 + wn + nt * 16 + l15;
            float bv = bias[n];
            #pragma unroll
            for (int mt = 0; mt < MT; mt++) {
                #pragma unroll
                for (int r = 0; r < 4; r++) {
                    int m = m0 + wm + mt * 16 + quad * 4 + r;   // D row = quad*4+reg
                    float val = acc[mt][nt][r] + bv;
                    if (C_MODE == 1) ((float*)C)[(size_t)m * N + n] = val;
                    else ((unsigned short*)C)[(size_t)m * N + n] = f2bf(val);
                }
            }
        }
    }
}

// Q,K,V projections + V-transpose batched: grid (256,1,3) = 768 blocks (~3/CU).
__global__ __launch_bounds__(256) void gemm_qkv(
    const unsigned short* __restrict__ Qb, const unsigned short* __restrict__ Kb,
    const unsigned short* __restrict__ Vb,
    const unsigned short* __restrict__ Wqb, const unsigned short* __restrict__ Wkb,
    const unsigned short* __restrict__ Wvb,
    const float* __restrict__ bq, const float* __restrict__ bk, const float* __restrict__ bv,
    unsigned short* __restrict__ Qp, unsigned short* __restrict__ Kp,
    unsigned short* __restrict__ Vt)
{
    __shared__ __align__(16) unsigned short sA[128 * 64];
    __shared__ __align__(16) unsigned short sB[128 * 64];
    const int z = blockIdx.z, id = blockIdx.x;
    if (z < 2) {
        gemm_core<0, 4>(z ? Kb : Qb, z ? Wkb : Wqb, z ? bk : bq, z ? Kp : Qp,
                        DMODEL, DMODEL, id & 7, id >> 3, sA, sB);
    } else {
        gemm_core<2, 4>(Wvb, Vb, bv, Vt, M_ROWS, DMODEL, id & 31, id >> 5, sA, sB);
    }
}

// Output projection: 64x128 tiles -> 512 blocks (2/CU hides the barrier drain).
__global__ __launch_bounds__(256) void gemm_o(
    const unsigned short* __restrict__ AO, const unsigned short* __restrict__ Wob,
    const float* __restrict__ bo, float* __restrict__ out)
{
    __shared__ __align__(16) unsigned short sA[64 * 64];
    __shared__ __align__(16) unsigned short sB[128 * 64];
    const int id = blockIdx.x;
    gemm_core<1, 2>(AO, Wob, bo, out, DMODEL, DMODEL, id & 7, id >> 3, sA, sB);
}

// ---------------- flash attention: 128-key tiles + register prefetch ----------------
// One block per (b, h, 64-query tile); 4 waves x 16 queries. No-max softmax
// (scores bounded; masked lanes exp2(-30000+x)==0). Next tile's K/V/mask are
// prefetched into registers during compute, so global latency is off the
// critical path; barriers: 3 per 128 keys (was 6).
__global__ __launch_bounds__(256) void attn_kernel(
    const unsigned short* __restrict__ Qp,
    const unsigned short* __restrict__ Kp,
    const unsigned short* __restrict__ Vt,
    const int* __restrict__ maskp,     // [B,T], nonzero = keep
    unsigned short* __restrict__ Op)
{
    __shared__ __align__(16) unsigned short sK[128 * LDT];      // [s][d]
    __shared__ __align__(16) unsigned short sV[64 * LDP];       // [d][s]
    __shared__ __align__(16) unsigned short sP[4 * 16 * LDP];   // per-wave P [q][s]
    __shared__ float smask[128];

    const int tid  = threadIdx.x;
    const int wave = tid >> 6, lane = tid & 63;
    const int quad = lane >> 4, l15 = lane & 15;
    const int qblk = blockIdx.x, h = blockIdx.y, b = blockIdx.z;

    const float SCL2 = 0.125f * 1.44269504089f;   // 1/sqrt(DK) * log2(e)
    const float MNEG = -30000.f;                  // exp2(-30000+x) == 0

    const int qrow = qblk * 64 + wave * 16 + l15;
    const unsigned short* qptr = Qp + (size_t)(b * T_SEQ + qrow) * DMODEL + h * DKH + quad * 8;
    const bf16x8 aq0 = *(const bf16x8*)qptr;
    const bf16x8 aq1 = *(const bf16x8*)(qptr + 32);

    const unsigned short* Kb_ = Kp + (size_t)b * T_SEQ * DMODEL + h * DKH;
    const unsigned short* VtB = Vt + ((size_t)b * DMODEL + h * DKH) * T_SEQ;

    f32x4 O[4] = {};
    float l_r[4] = {0.f, 0.f, 0.f, 0.f};
    unsigned short* sPw = sP + wave * 16 * LDP;

    // per-thread staging chunk coords (4 chunks each for K and V)
    int krow[4], koff[4], vrow[4], voff[4];
    #pragma unroll
    for (int i = 0; i < 4; i++) {
        int c = tid + 256 * i;
        krow[i] = c >> 3;  koff[i] = (c & 7) * 8;    // K: 128 rows x 64 d
        vrow[i] = c >> 4;  voff[i] = (c & 15) * 8;   // V: 64 rows x 128 s
    }

    // ---- prefetch tile 0 ----
    uint4 kr[4], vr[4]; int mreg = 0;
    #pragma unroll
    for (int i = 0; i < 4; i++) {
        kr[i] = *(const uint4*)&Kb_[(size_t)krow[i] * DMODEL + koff[i]];
        vr[i] = *(const uint4*)&VtB[(size_t)vrow[i] * T_SEQ + voff[i]];
    }
    if (tid < 128) mreg = maskp[b * T_SEQ + tid];

    for (int it = 0; it < T_SEQ / 128; it++) {
        const int s0 = it * 128;
        __syncthreads();   // previous tile's MFMA reads of sK/sV/sP done
        #pragma unroll
        for (int i = 0; i < 4; i++) {
            *(uint4*)&sK[krow[i] * LDT + koff[i]] = kr[i];
            *(uint4*)&sV[vrow[i] * LDP + voff[i]] = vr[i];
        }
        if (tid < 128) smask[tid] = mreg ? 0.f : MNEG;
        __syncthreads();

        // ---- issue next tile's prefetch (latency overlapped with compute) ----
        const int sn = (s0 + 128) & (T_SEQ - 1);
        #pragma unroll
        for (int i = 0; i < 4; i++) {
            kr[i] = *(const uint4*)&Kb_[(size_t)(sn + krow[i]) * DMODEL + koff[i]];
            vr[i] = *(const uint4*)&VtB[(size_t)vrow[i] * T_SEQ + sn + voff[i]];
        }
        if (tid < 128) mreg = maskp[b * T_SEQ + sn + tid];

        // ---- S = Q K^T (C-layout: row=query=quad*4+r, col=key=nt*16+l15) ----
        f32x4 S[8];
        #pragma unroll
        for (int nt = 0; nt < 8; nt++) {
            const unsigned short* kb = &sK[(nt * 16 + l15) * LDT + quad * 8];
            f32x4 z = {};
            z = __builtin_amdgcn_mfma_f32_16x16x32_bf16(aq0, *(const bf16x8*)kb, z, 0, 0, 0);
            z = __builtin_amdgcn_mfma_f32_16x16x32_bf16(aq1, *(const bf16x8*)(kb + 32), z, 0, 0, 0);
            S[nt] = z;
        }

        // ---- p = exp2(s*c + madd); no max, no shuffles ----
        #pragma unroll
        for (int nt = 0; nt < 8; nt++) {
            float madd = smask[nt * 16 + l15];
            #pragma unroll
            for (int r = 0; r < 4; r++) {
                float p = __builtin_amdgcn_exp2f(fmaf(S[nt][r], SCL2, madd));
                l_r[r] += p;
                unsigned u = __builtin_bit_cast(unsigned, p) + 0x8000u;  // round-half-up
                sPw[(quad * 4 + r) * LDP + nt * 16 + l15] = (unsigned short)(u >> 16);
            }
        }
        __syncthreads();   // P visible before A-operand reads

        // ---- O += P V  (A = P rows, B = V^T rows) ----
        #pragma unroll
        for (int ksc = 0; ksc < 4; ksc++) {
            const bf16x8 ap = *(const bf16x8*)&sPw[l15 * LDP + ksc * 32 + quad * 8];
            #pragma unroll
            for (int nt = 0; nt < 4; nt++) {
                const unsigned short* vb = &sV[(nt * 16 + l15) * LDP + ksc * 32 + quad * 8];
                O[nt] = __builtin_amdgcn_mfma_f32_16x16x32_bf16(ap, *(const bf16x8*)vb, O[nt], 0, 0, 0);
            }
        }
    }

    // ---- row-sum reduce, normalize, write AO [B,T,D] ----
    #pragma unroll
    for (int r = 0; r < 4; r++) {
        float l = l_r[r];
        l += __shfl_xor(l, 1);
        l += __shfl_xor(l, 2);
        l += __shfl_xor(l, 4);
        l += __shfl_xor(l, 8);
        l_r[r] = 1.0f / fmaxf(l, 1e-30f);
    }
    #pragma unroll
    for (int nt = 0; nt < 4; nt++) {
        #pragma unroll
        for (int r = 0; r < 4; r++) {
            int q = qblk * 64 + wave * 16 + quad * 4 + r;
            Op[(size_t)(b * T_SEQ + q) * DMODEL + h * DKH + nt * 16 + l15] =
                f2bf(O[nt][r] * l_r[r]);
        }
    }
}

// ---------------- legacy fp32-staging GEMM (fallback path only) ----------------
template<int A_BF16, int W_BF16, int C_MODE>
__global__ __launch_bounds__(256) void gemm_bt_cvt(
    const void* __restrict__ A_, const void* __restrict__ W_,
    const float* __restrict__ bias, void* __restrict__ C_,
    int M, int N, int K)
{
    __shared__ __align__(16) unsigned short sA[128 * LDT];
    __shared__ __align__(16) unsigned short sB[128 * LDT];
    const int tid  = threadIdx.x;
    const int wave = tid >> 6, lane = tid & 63;
    const int quad = lane >> 4, l15 = lane & 15;
    const int m0 = blockIdx.y * 128, n0 = blockIdx.x * 128;
    const int wm = (wave & 1) * 64, wn = (wave >> 1) * 64;
    f32x4 acc[4][4] = {};
    for (int k0 = 0; k0 < K; k0 += 64) {
        __syncthreads();
        #pragma unroll
        for (int i = 0; i < 4; i++) {
            int c = tid + 256 * i;
            int row = c >> 3, koff = (c & 7) * 8;
            if (A_BF16)
                *(uint4*)&sA[row * LDT + koff] =
                    *(const uint4*)&((const unsigned short*)A_)[(size_t)(m0 + row) * K + k0 + koff];
            else
                *(uint4*)&sA[row * LDT + koff] =
                    cvt8((const float*)A_ + (size_t)(m0 + row) * K + k0 + koff);
            if (W_BF16)
                *(uint4*)&sB[row * LDT + koff] =
                    *(const uint4*)&((const unsigned short*)W_)[(size_t)(n0 + row) * K + k0 + koff];
            else
                *(uint4*)&sB[row * LDT + koff] =
                    cvt8((const float*)W_ + (size_t)(n0 + row) * K + k0 + koff);
        }
        __syncthreads();
        #pragma unroll
        for (int ks = 0; ks < 2; ks++) {
            bf16x8 af[4], bfr[4];
            #pragma unroll
            for (int mt = 0; mt < 4; mt++)
                af[mt] = *(const bf16x8*)&sA[(wm + mt * 16 + l15) * LDT + ks * 32 + quad * 8];
            #pragma unroll
            for (int nt = 0; nt < 4; nt++)
                bfr[nt] = *(const bf16x8*)&sB[(wn + nt * 16 + l15) * LDT + ks * 32 + quad * 8];
            #pragma unroll
            for (int mt = 0; mt < 4; mt++)
                #pragma unroll
                for (int nt = 0; nt < 4; nt++)
                    acc[mt][nt] = __builtin_amdgcn_mfma_f32_16x16x32_bf16(
                        af[mt], bfr[nt], acc[mt][nt], 0, 0, 0);
        }
    }
    if (C_MODE == 2) {
        #pragma unroll
        for (int mt = 0; mt < 4; mt++)
            #pragma unroll
            for (int r = 0; r < 4; r++) {
                int m = m0 + wm + mt * 16 + quad * 4 + r;
                float bm = bias[m];
                #pragma unroll
                for (int nt = 0; nt < 4; nt++) {
                    int n = n0 + wn + nt * 16 + l15;
                    int bb = n >> 11, t = n & 2047;
                    ((unsigned short*)C_)[((size_t)bb * 1024 + m) * 2048 + t] =
                        f2bf(acc[mt][nt][r] + bm);
                }
            }
    } else {
        #pragma unroll
        for (int nt = 0; nt < 4; nt++) {
            int n = n0 + wn + nt * 16 + l15;
            float bv = bias[n];
            #pragma unroll
            for (int mt = 0; mt < 4; mt++)
                #pragma unroll
                for (int r = 0; r < 4; r++) {
                    int m = m0 + wm + mt * 16 + quad * 4 + r;
                    float val = acc[mt][nt][r] + bv;
                    if (C_MODE == 1) ((float*)C_)[(size_t)m * N + n] = val;
                    else ((unsigned short*)C_)[(size_t)m * N + n] = f2bf(val);
                }
        }
    }
}

extern "C" void kernel_launch(void* const* d_in, const int* in_sizes, int n_in,
                              void* d_out, int out_size, void* d_ws, size_t ws_size,
                              hipStream_t stream)
{
    const float* q  = (const float*)d_in[0];
    const float* k  = (const float*)d_in[1];
    const float* v  = (const float*)d_in[2];
    const int*   mk = (const int*)d_in[3];
    const float* Wq = (const float*)d_in[4];
    const float* bq = (const float*)d_in[5];
    const float* Wk = (const float*)d_in[6];
    const float* bk = (const float*)d_in[7];
    const float* Wv = (const float*)d_in[8];
    const float* bv = (const float*)d_in[9];
    const float* Wo = (const float*)d_in[10];
    const float* bo = (const float*)d_in[11];
    float* out = (float*)d_out;

    unsigned short* wsb = (unsigned short*)d_ws;
    const dim3 gA(T_SEQ / 64, NHEAD, B_SZ);

    if (ws_size >= (size_t)64 * 1024 * 1024) {
        // Path A: pre-convert to bf16; m97-style global_load_lds GEMMs.
        unsigned short* Qb  = wsb;
        unsigned short* Kb  = wsb + INP_E;
        unsigned short* Vb  = wsb + 2 * INP_E;
        unsigned short* Wqb = wsb + 3 * INP_E;
        unsigned short* Wkb = wsb + 3 * INP_E + W_E;
        unsigned short* Wvb = wsb + 3 * INP_E + 2 * W_E;
        unsigned short* Wob = wsb + 3 * INP_E + 3 * W_E;
        unsigned short* Qp  = wsb + 4 * INP_E;
        unsigned short* Kp  = wsb + 5 * INP_E;
        unsigned short* Vt  = wsb + 6 * INP_E;
        unsigned short* AO  = wsb + 7 * INP_E;       // end = 64MB

        cvt_all<<<8192, 256, 0, stream>>>(q, k, v, Wq, Wk, Wv, Wo, wsb);
        gemm_qkv<<<dim3(256, 1, 3), 256, 0, stream>>>(
            Qb, Kb, Vb, Wqb, Wkb, Wvb, bq, bk, bv, Qp, Kp, Vt);
        attn_kernel<<<gA, 256, 0, stream>>>(Qp, Kp, Vt, mk, AO);
        gemm_o<<<dim3(512, 1, 1), 256, 0, stream>>>(AO, Wob, bo, out);
    } else {
        // Path C fallback: in-GEMM convert (32MB ws), legacy kernels.
        unsigned short* Qp = wsb;
        unsigned short* Kp = wsb + INP_E;
        unsigned short* Vt = wsb + 2 * INP_E;
        unsigned short* AO = wsb + 3 * INP_E;
        const dim3 gN(DMODEL / 128, M_ROWS / 128);
        const dim3 gV(M_ROWS / 128, DMODEL / 128);
        gemm_bt_cvt<0, 0, 0><<<gN, 256, 0, stream>>>(q, Wq, bq, Qp, M_ROWS, DMODEL, DMODEL);
        gemm_bt_cvt<0, 0, 0><<<gN, 256, 0, stream>>>(k, Wk, bk, Kp, M_ROWS, DMODEL, DMODEL);
        gemm_bt_cvt<0, 0, 2><<<gV, 256, 0, stream>>>(Wv, v, bv, Vt, DMODEL, M_ROWS, DMODEL);
        attn_kernel<<<gA, 256, 0, stream>>>(Qp, Kp, Vt, mk, AO);
        gemm_bt_cvt<1, 0, 1><<<gN, 256, 0, stream>>>(AO, Wo, bo, out, M_ROWS, DMODEL, DMODEL);
    }
}

// Round 8
// 244.140 us; speedup vs baseline: 1.4268x; 1.4268x over previous
//
#include <hip/hip_runtime.h>
#include <stdint.h>

// Problem constants (B,T,D,H fixed by the reference)
#define B_SZ 2
#define T_SEQ 2048
#define DMODEL 1024
#define NHEAD 16
#define DKH 64
#define M_ROWS (B_SZ * T_SEQ)   // 4096

#define LDT 72    // padded LDS row stride (bf16) for VALU-written tiles (sP): 2-way = free

#define INP_E  4194304u   // 4M elems per input tensor
#define W_E    1048576u   // 1M elems per weight

typedef __bf16 bf16x8 __attribute__((ext_vector_type(8)));
typedef float  f32x4  __attribute__((ext_vector_type(4)));

__device__ __forceinline__ unsigned short f2bf(float f) {
    unsigned u = __builtin_bit_cast(unsigned, f);
    u += 0x7fffu + ((u >> 16) & 1u);   // RNE
    return (unsigned short)(u >> 16);
}
// 8 consecutive fp32 -> 8 bf16 packed in a uint4
__device__ __forceinline__ uint4 cvt8(const float* p) {
    float4 f0 = *(const float4*)p, f1 = *(const float4*)(p + 4);
    uint4 r;
    r.x = (unsigned)f2bf(f0.x) | ((unsigned)f2bf(f0.y) << 16);
    r.y = (unsigned)f2bf(f0.z) | ((unsigned)f2bf(f0.w) << 16);
    r.z = (unsigned)f2bf(f1.x) | ((unsigned)f2bf(f1.y) << 16);
    r.w = (unsigned)f2bf(f1.z) | ((unsigned)f2bf(f1.w) << 16);
    return r;
}

// Async global->LDS, 16B per lane. LDS dest = wave-uniform base + lane*16 (m104/m108).
__device__ __forceinline__ void async16(const unsigned short* g, unsigned short* l) {
    __builtin_amdgcn_global_load_lds(
        (const __attribute__((address_space(1))) void*)g,
        (__attribute__((address_space(3))) void*)l, 16, 0, 0);
}

// One-shot fp32 -> bf16 conversion of q,k,v + 4 weights into ws.
__global__ __launch_bounds__(256) void cvt_all(
    const float* __restrict__ q, const float* __restrict__ k, const float* __restrict__ v,
    const float* __restrict__ wq, const float* __restrict__ wk,
    const float* __restrict__ wv, const float* __restrict__ wo,
    unsigned short* __restrict__ wsb)
{
    int blk = blockIdx.x;
    const float* src; unsigned short* dst; int lb;
    if      (blk < 2048) { src = q;  dst = wsb;                       lb = blk; }
    else if (blk < 4096) { src = k;  dst = wsb + INP_E;               lb = blk - 2048; }
    else if (blk < 6144) { src = v;  dst = wsb + 2 * INP_E;           lb = blk - 4096; }
    else if (blk < 6656) { src = wq; dst = wsb + 3 * INP_E;           lb = blk - 6144; }
    else if (blk < 7168) { src = wk; dst = wsb + 3 * INP_E + W_E;     lb = blk - 6656; }
    else if (blk < 7680) { src = wv; dst = wsb + 3 * INP_E + 2 * W_E; lb = blk - 7168; }
    else                 { src = wo; dst = wsb + 3 * INP_E + 3 * W_E; lb = blk - 7680; }
    size_t i = ((size_t)lb * 256 + threadIdx.x) * 8;
    *(uint4*)&dst[i] = cvt8(src + i);
}

// ---------------- m97-style GEMM core ----------------
// D[m][n] = sum_k A[m][k]*W[n][k] + bias. Tile (MT*32) x 128, BK=64,
// global_load_lds width=16 into UNPADDED stride-64 LDS with XOR column-chunk
// swizzle (LDS[row][j] holds global chunk j^(row&7); reads un-swizzle).
// C_MODE: 0 = bf16 C[m*N+n] (bias[n]); 1 = fp32 C (bias[n]);
//         2 = Vt[(b*1024+m)*2048 + t] (bias[m], transposed store).
template<int C_MODE, int MT>
__device__ __forceinline__ void gemm_core(
    const unsigned short* __restrict__ A, const unsigned short* __restrict__ W,
    const float* __restrict__ bias, void* __restrict__ C,
    int N, int K, int bx, int by,
    unsigned short* sA, unsigned short* sB)
{
    const int tid  = threadIdx.x;
    const int wave = tid >> 6, lane = tid & 63;
    const int quad = lane >> 4, l15 = lane & 15;
    const int TM = MT * 32;
    const int m0 = by * TM, n0 = bx * 128;
    const int wm = (wave & 1) * (MT * 16), wn = (wave >> 1) * 64;

    f32x4 acc[MT][4] = {};

    for (int k0 = 0; k0 < K; k0 += 64) {
        __syncthreads();                      // prev iteration's LDS reads done
        #pragma unroll
        for (int i = 0; i < MT; i++) {        // A: TM rows x 8 chunks
            int c   = tid + 256 * i;
            int row = c >> 3;
            int gk  = ((c & 7) ^ (row & 7)) * 8;
            int sb  = (wave * 64 + 256 * i) * 8;
            async16(&A[(size_t)(m0 + row) * K + k0 + gk], sA + sb);
        }
        #pragma unroll
        for (int i = 0; i < 4; i++) {         // B: 128 rows x 8 chunks
            int c   = tid + 256 * i;
            int row = c >> 3;
            int gk  = ((c & 7) ^ (row & 7)) * 8;
            int sb  = (wave * 64 + 256 * i) * 8;
            async16(&W[(size_t)(n0 + row) * K + k0 + gk], sB + sb);
        }
        __syncthreads();                      // drains vmcnt(0): data landed
        const int sw = l15 & 7;
        #pragma unroll
        for (int ks = 0; ks < 2; ks++) {
            bf16x8 af[MT], bfv[4];
            #pragma unroll
            for (int mt = 0; mt < MT; mt++)
                af[mt] = *(const bf16x8*)&sA[(wm + mt * 16 + l15) * 64 +
                                             (((ks * 4 + quad) ^ sw) * 8)];
            #pragma unroll
            for (int nt = 0; nt < 4; nt++)
                bfv[nt] = *(const bf16x8*)&sB[(wn + nt * 16 + l15) * 64 +
                                              (((ks * 4 + quad) ^ sw) * 8)];
            #pragma unroll
            for (int mt = 0; mt < MT; mt++)
                #pragma unroll
                for (int nt = 0; nt < 4; nt++)
                    acc[mt][nt] = __builtin_amdgcn_mfma_f32_16x16x32_bf16(
                        af[mt], bfv[nt], acc[mt][nt], 0, 0, 0);
        }
    }

    if (C_MODE == 2) {
        #pragma unroll
        for (int mt = 0; mt < MT; mt++) {
            #pragma unroll
            for (int r = 0; r < 4; r++) {
                int m = m0 + wm + mt * 16 + quad * 4 + r;
                float bm = bias[m];
                #pragma unroll
                for (int nt = 0; nt < 4; nt++) {
                    int n = n0 + wn + nt * 16 + l15;
                    int bb = n >> 11, t = n & 2047;
                    ((unsigned short*)C)[((size_t)bb * 1024 + m) * 2048 + t] =
                        f2bf(acc[mt][nt][r] + bm);
                }
            }
        }
    } else {
        #pragma unroll
        for (int nt = 0; nt < 4; nt++) {
            int n = n0 + wn + nt * 16 + l15;
            float bv = bias[n];
            #pragma unroll
            for (int mt = 0; mt < MT; mt++) {
                #pragma unroll
                for (int r = 0; r < 4; r++) {
                    int m = m0 + wm + mt * 16 + quad * 4 + r;   // D row = quad*4+reg
                    float val = acc[mt][nt][r] + bv;
                    if (C_MODE == 1) ((float*)C)[(size_t)m * N + n] = val;
                    else ((unsigned short*)C)[(size_t)m * N + n] = f2bf(val);
                }
            }
        }
    }
}

// Q,K,V projections + V-transpose batched: grid (256,1,3) = 768 blocks (~3/CU).
__global__ __launch_bounds__(256) void gemm_qkv(
    const unsigned short* __restrict__ Qb, const unsigned short* __restrict__ Kb,
    const unsigned short* __restrict__ Vb,
    const unsigned short* __restrict__ Wqb, const unsigned short* __restrict__ Wkb,
    const unsigned short* __restrict__ Wvb,
    const float* __restrict__ bq, const float* __restrict__ bk, const float* __restrict__ bv,
    unsigned short* __restrict__ Qp, unsigned short* __restrict__ Kp,
    unsigned short* __restrict__ Vt)
{
    __shared__ __align__(16) unsigned short sA[128 * 64];
    __shared__ __align__(16) unsigned short sB[128 * 64];
    const int z = blockIdx.z, id = blockIdx.x;
    if (z < 2) {
        gemm_core<0, 4>(z ? Kb : Qb, z ? Wkb : Wqb, z ? bk : bq, z ? Kp : Qp,
                        DMODEL, DMODEL, id & 7, id >> 3, sA, sB);
    } else {
        gemm_core<2, 4>(Wvb, Vb, bv, Vt, M_ROWS, DMODEL, id & 31, id >> 5, sA, sB);
    }
}

// Output projection: 64x128 tiles -> 512 blocks (2/CU hides the barrier drain).
__global__ __launch_bounds__(256) void gemm_o(
    const unsigned short* __restrict__ AO, const unsigned short* __restrict__ Wob,
    const float* __restrict__ bo, float* __restrict__ out)
{
    __shared__ __align__(16) unsigned short sA[64 * 64];
    __shared__ __align__(16) unsigned short sB[128 * 64];
    const int id = blockIdx.x;
    gemm_core<1, 2>(AO, Wob, bo, out, DMODEL, DMODEL, id & 7, id >> 3, sA, sB);
}

// ---------------- flash attention: 64-key tiles, async LDS staging ----------------
// Round-6 structure (known 83 us) with the staging VGPR round-trip removed:
// K and V^T tiles go global->LDS via global_load_lds width=16 into UNPADDED
// stride-64 LDS with the same XOR chunk swizzle as gemm_core (reads un-swizzle
// with ^(l15&7): 32 banks, 2-way = free). No extra register pressure (the
// round-7 register-prefetch variant spilled 450 MB to scratch — never again).
__global__ __launch_bounds__(256) void attn_kernel(
    const unsigned short* __restrict__ Qp,
    const unsigned short* __restrict__ Kp,
    const unsigned short* __restrict__ Vt,
    const int* __restrict__ maskp,     // [B,T], nonzero = keep
    unsigned short* __restrict__ Op)
{
    __shared__ __align__(16) unsigned short sK[64 * 64];        // [s][d], swizzled
    __shared__ __align__(16) unsigned short sV[64 * 64];        // [d][s], swizzled
    __shared__ __align__(16) unsigned short sP[4 * 16 * LDT];   // per-wave P [q][s], padded
    __shared__ float smask[64];

    const int tid  = threadIdx.x;
    const int wave = tid >> 6, lane = tid & 63;
    const int quad = lane >> 4, l15 = lane & 15;
    const int qblk = blockIdx.x, h = blockIdx.y, b = blockIdx.z;

    const float SCL2 = 0.125f * 1.44269504089f;   // 1/sqrt(DK) * log2(e)
    const float MNEG = -30000.f;                  // exp2(-30000+x) == 0

    const int qrow = qblk * 64 + wave * 16 + l15;
    const unsigned short* qptr = Qp + (size_t)(b * T_SEQ + qrow) * DMODEL + h * DKH + quad * 8;
    const bf16x8 aq0 = *(const bf16x8*)qptr;
    const bf16x8 aq1 = *(const bf16x8*)(qptr + 32);

    const unsigned short* Kb_ = Kp + (size_t)b * T_SEQ * DMODEL + h * DKH;
    const unsigned short* VtB = Vt + ((size_t)b * DMODEL + h * DKH) * T_SEQ;

    f32x4 O[4] = {};
    float l_r[4] = {0.f, 0.f, 0.f, 0.f};
    unsigned short* sPw = sP + wave * 16 * LDT;

    for (int s0 = 0; s0 < T_SEQ; s0 += 64) {
        __syncthreads();   // previous tile's MFMA reads of sK/sV done
        // ---- async-stage K [s][d] and V^T [d][s]; 512 chunks of 16B each ----
        #pragma unroll
        for (int i = 0; i < 2; i++) {
            int c   = tid + 256 * i;
            int row = c >> 3;
            int gk  = ((c & 7) ^ (row & 7)) * 8;   // swizzled global chunk
            int sb  = (wave * 64 + 256 * i) * 8;   // wave-uniform LDS base (elems)
            async16(&Kb_[(size_t)(s0 + row) * DMODEL + gk], sK + sb);
            async16(&VtB[(size_t)row * T_SEQ + s0 + gk], sV + sb);
        }
        if (tid < 64)
            smask[tid] = maskp[b * T_SEQ + s0 + tid] ? 0.f : MNEG;
        __syncthreads();   // drains vmcnt: K/V landed; smask visible

        const int sw = l15 & 7;
        // ---- S = Q K^T (C-layout: row=query=quad*4+r, col=key=nt*16+l15) ----
        f32x4 S[4];
        #pragma unroll
        for (int nt = 0; nt < 4; nt++) {
            const unsigned short* kr = &sK[(nt * 16 + l15) * 64];
            f32x4 z = {};
            z = __builtin_amdgcn_mfma_f32_16x16x32_bf16(
                aq0, *(const bf16x8*)&kr[(quad ^ sw) * 8], z, 0, 0, 0);
            z = __builtin_amdgcn_mfma_f32_16x16x32_bf16(
                aq1, *(const bf16x8*)&kr[((quad + 4) ^ sw) * 8], z, 0, 0, 0);
            S[nt] = z;
        }

        // ---- p = exp2(s*c + madd); no max, no shuffles ----
        #pragma unroll
        for (int nt = 0; nt < 4; nt++) {
            float madd = smask[nt * 16 + l15];
            #pragma unroll
            for (int r = 0; r < 4; r++) {
                float p = __builtin_amdgcn_exp2f(fmaf(S[nt][r], SCL2, madd));
                l_r[r] += p;
                unsigned u = __builtin_bit_cast(unsigned, p) + 0x8000u;  // round-half-up
                sPw[(quad * 4 + r) * LDT + nt * 16 + l15] = (unsigned short)(u >> 16);
            }
        }
        __syncthreads();   // P visible before A-operand reads

        // ---- O += P V  (A = P rows, B = V^T rows) ----
        const bf16x8 ap0 = *(const bf16x8*)&sPw[l15 * LDT + quad * 8];
        const bf16x8 ap1 = *(const bf16x8*)&sPw[l15 * LDT + 32 + quad * 8];
        #pragma unroll
        for (int nt = 0; nt < 4; nt++) {
            const unsigned short* vr = &sV[(nt * 16 + l15) * 64];
            O[nt] = __builtin_amdgcn_mfma_f32_16x16x32_bf16(
                ap0, *(const bf16x8*)&vr[(quad ^ sw) * 8], O[nt], 0, 0, 0);
            O[nt] = __builtin_amdgcn_mfma_f32_16x16x32_bf16(
                ap1, *(const bf16x8*)&vr[((quad + 4) ^ sw) * 8], O[nt], 0, 0, 0);
        }
    }

    // ---- row-sum reduce, normalize, write AO [B,T,D] ----
    #pragma unroll
    for (int r = 0; r < 4; r++) {
        float l = l_r[r];
        l += __shfl_xor(l, 1);
        l += __shfl_xor(l, 2);
        l += __shfl_xor(l, 4);
        l += __shfl_xor(l, 8);
        l_r[r] = 1.0f / fmaxf(l, 1e-30f);
    }
    #pragma unroll
    for (int nt = 0; nt < 4; nt++) {
        #pragma unroll
        for (int r = 0; r < 4; r++) {
            int q = qblk * 64 + wave * 16 + quad * 4 + r;
            Op[(size_t)(b * T_SEQ + q) * DMODEL + h * DKH + nt * 16 + l15] =
                f2bf(O[nt][r] * l_r[r]);
        }
    }
}

// ---------------- legacy fp32-staging GEMM (fallback path only) ----------------
template<int A_BF16, int W_BF16, int C_MODE>
__global__ __launch_bounds__(256) void gemm_bt_cvt(
    const void* __restrict__ A_, const void* __restrict__ W_,
    const float* __restrict__ bias, void* __restrict__ C_,
    int M, int N, int K)
{
    __shared__ __align__(16) unsigned short sA[128 * LDT];
    __shared__ __align__(16) unsigned short sB[128 * LDT];
    const int tid  = threadIdx.x;
    const int wave = tid >> 6, lane = tid & 63;
    const int quad = lane >> 4, l15 = lane & 15;
    const int m0 = blockIdx.y * 128, n0 = blockIdx.x * 128;
    const int wm = (wave & 1) * 64, wn = (wave >> 1) * 64;
    f32x4 acc[4][4] = {};
    for (int k0 = 0; k0 < K; k0 += 64) {
        __syncthreads();
        #pragma unroll
        for (int i = 0; i < 4; i++) {
            int c = tid + 256 * i;
            int row = c >> 3, koff = (c & 7) * 8;
            if (A_BF16)
                *(uint4*)&sA[row * LDT + koff] =
                    *(const uint4*)&((const unsigned short*)A_)[(size_t)(m0 + row) * K + k0 + koff];
            else
                *(uint4*)&sA[row * LDT + koff] =
                    cvt8((const float*)A_ + (size_t)(m0 + row) * K + k0 + koff);
            if (W_BF16)
                *(uint4*)&sB[row * LDT + koff] =
                    *(const uint4*)&((const unsigned short*)W_)[(size_t)(n0 + row) * K + k0 + koff];
            else
                *(uint4*)&sB[row * LDT + koff] =
                    cvt8((const float*)W_ + (size_t)(n0 + row) * K + k0 + koff);
        }
        __syncthreads();
        #pragma unroll
        for (int ks = 0; ks < 2; ks++) {
            bf16x8 af[4], bfr[4];
            #pragma unroll
            for (int mt = 0; mt < 4; mt++)
                af[mt] = *(const bf16x8*)&sA[(wm + mt * 16 + l15) * LDT + ks * 32 + quad * 8];
            #pragma unroll
            for (int nt = 0; nt < 4; nt++)
                bfr[nt] = *(const bf16x8*)&sB[(wn + nt * 16 + l15) * LDT + ks * 32 + quad * 8];
            #pragma unroll
            for (int mt = 0; mt < 4; mt++)
                #pragma unroll
                for (int nt = 0; nt < 4; nt++)
                    acc[mt][nt] = __builtin_amdgcn_mfma_f32_16x16x32_bf16(
                        af[mt], bfr[nt], acc[mt][nt], 0, 0, 0);
        }
    }
    if (C_MODE == 2) {
        #pragma unroll
        for (int mt = 0; mt < 4; mt++)
            #pragma unroll
            for (int r = 0; r < 4; r++) {
                int m = m0 + wm + mt * 16 + quad * 4 + r;
                float bm = bias[m];
                #pragma unroll
                for (int nt = 0; nt < 4; nt++) {
                    int n = n0 + wn + nt * 16 + l15;
                    int bb = n >> 11, t = n & 2047;
                    ((unsigned short*)C_)[((size_t)bb * 1024 + m) * 2048 + t] =
                        f2bf(acc[mt][nt][r] + bm);
                }
            }
    } else {
        #pragma unroll
        for (int nt = 0; nt < 4; nt++) {
            int n = n0 + wn + nt * 16 + l15;
            float bv = bias[n];
            #pragma unroll
            for (int mt = 0; mt < 4; mt++)
                #pragma unroll
                for (int r = 0; r < 4; r++) {
                    int m = m0 + wm + mt * 16 + quad * 4 + r;
                    float val = acc[mt][nt][r] + bv;
                    if (C_MODE == 1) ((float*)C_)[(size_t)m * N + n] = val;
                    else ((unsigned short*)C_)[(size_t)m * N + n] = f2bf(val);
                }
        }
    }
}

extern "C" void kernel_launch(void* const* d_in, const int* in_sizes, int n_in,
                              void* d_out, int out_size, void* d_ws, size_t ws_size,
                              hipStream_t stream)
{
    const float* q  = (const float*)d_in[0];
    const float* k  = (const float*)d_in[1];
    const float* v  = (const float*)d_in[2];
    const int*   mk = (const int*)d_in[3];
    const float* Wq = (const float*)d_in[4];
    const float* bq = (const float*)d_in[5];
    const float* Wk = (const float*)d_in[6];
    const float* bk = (const float*)d_in[7];
    const float* Wv = (const float*)d_in[8];
    const float* bv = (const float*)d_in[9];
    const float* Wo = (const float*)d_in[10];
    const float* bo = (const float*)d_in[11];
    float* out = (float*)d_out;

    unsigned short* wsb = (unsigned short*)d_ws;
    const dim3 gA(T_SEQ / 64, NHEAD, B_SZ);

    if (ws_size >= (size_t)64 * 1024 * 1024) {
        // Path A: pre-convert to bf16; m97-style global_load_lds GEMMs.
        unsigned short* Qb  = wsb;
        unsigned short* Kb  = wsb + INP_E;
        unsigned short* Vb  = wsb + 2 * INP_E;
        unsigned short* Wqb = wsb + 3 * INP_E;
        unsigned short* Wkb = wsb + 3 * INP_E + W_E;
        unsigned short* Wvb = wsb + 3 * INP_E + 2 * W_E;
        unsigned short* Wob = wsb + 3 * INP_E + 3 * W_E;
        unsigned short* Qp  = wsb + 4 * INP_E;
        unsigned short* Kp  = wsb + 5 * INP_E;
        unsigned short* Vt  = wsb + 6 * INP_E;
        unsigned short* AO  = wsb + 7 * INP_E;       // end = 64MB

        cvt_all<<<8192, 256, 0, stream>>>(q, k, v, Wq, Wk, Wv, Wo, wsb);
        gemm_qkv<<<dim3(256, 1, 3), 256, 0, stream>>>(
            Qb, Kb, Vb, Wqb, Wkb, Wvb, bq, bk, bv, Qp, Kp, Vt);
        attn_kernel<<<gA, 256, 0, stream>>>(Qp, Kp, Vt, mk, AO);
        gemm_o<<<dim3(512, 1, 1), 256, 0, stream>>>(AO, Wob, bo, out);
    } else {
        // Path C fallback: in-GEMM convert (32MB ws), legacy kernels.
        unsigned short* Qp = wsb;
        unsigned short* Kp = wsb + INP_E;
        unsigned short* Vt = wsb + 2 * INP_E;
        unsigned short* AO = wsb + 3 * INP_E;
        const dim3 gN(DMODEL / 128, M_ROWS / 128);
        const dim3 gV(M_ROWS / 128, DMODEL / 128);
        gemm_bt_cvt<0, 0, 0><<<gN, 256, 0, stream>>>(q, Wq, bq, Qp, M_ROWS, DMODEL, DMODEL);
        gemm_bt_cvt<0, 0, 0><<<gN, 256, 0, stream>>>(k, Wk, bk, Kp, M_ROWS, DMODEL, DMODEL);
        gemm_bt_cvt<0, 0, 2><<<gV, 256, 0, stream>>>(Wv, v, bv, Vt, DMODEL, M_ROWS, DMODEL);
        attn_kernel<<<gA, 256, 0, stream>>>(Qp, Kp, Vt, mk, AO);
        gemm_bt_cvt<1, 0, 1><<<gN, 256, 0, stream>>>(AO, Wo, bo, out, M_ROWS, DMODEL, DMODEL);
    }
}